// Round 13
// baseline (468.699 us; speedup 1.0000x reference)
//
#include <hip/hip_runtime.h>
#include <hip/hip_bf16.h>
#include <hip/hip_fp16.h>

#define HEADS 3

union HU { uint4 u; __half2 h[4]; };

// ---------------------------------------------------------------- prep: ce[h] = sum_d We[h*D+d] * ae[h*D+d]
__global__ void prep_ce_kernel(const float* __restrict__ We1, const float* __restrict__ ae1,
                               const float* __restrict__ We2, const float* __restrict__ ae2,
                               const float* __restrict__ We3, const float* __restrict__ ae3,
                               float* __restrict__ ce) {
    int t = threadIdx.x;
    if (t >= 9) return;
    int l = t / 3, h = t % 3;
    const float* We = (l == 0) ? We1 : (l == 1) ? We2 : We3;
    const float* ae = (l == 0) ? ae1 : (l == 1) ? ae2 : ae3;
    int D = (l == 0) ? 8 : (l == 1) ? 16 : 32;
    float s = 0.f;
    for (int d = 0; d < D; d++) s += We[h * D + d] * ae[h * D + d];
    ce[t] = s;
}

// ---------------------------------------------------------------- CSR build
__global__ void hist_rank_kernel(const int* __restrict__ dst, int* __restrict__ deg,
                                 int* __restrict__ rank, int E) {
    int tid = blockIdx.x * blockDim.x + threadIdx.x;
    if (tid < E) {
        int r = atomicAdd(&deg[dst[tid]], 1);
        __builtin_nontemporal_store(r, &rank[tid]);
    }
}

#define SCAN_BLK 1024
__global__ void scan1_kernel(const int* __restrict__ deg, int* __restrict__ row_ptr,
                             int* __restrict__ partials, int N) {
    __shared__ int sm[SCAN_BLK];
    int t = threadIdx.x;
    int g = blockIdx.x * SCAN_BLK + t;
    int v = (g < N) ? deg[g] : 0;
    sm[t] = v;
    __syncthreads();
    for (int off = 1; off < SCAN_BLK; off <<= 1) {
        int x = (t >= off) ? sm[t - off] : 0;
        __syncthreads();
        sm[t] += x;
        __syncthreads();
    }
    if (g < N) row_ptr[g] = sm[t] - v;   // exclusive
    if (t == SCAN_BLK - 1) partials[blockIdx.x] = sm[t];
}

__global__ void scan2_kernel(int* __restrict__ partials, int NB) {
    __shared__ int sm[128];
    int t = threadIdx.x;
    int v = (t < NB) ? partials[t] : 0;
    sm[t] = v;
    __syncthreads();
    for (int off = 1; off < 128; off <<= 1) {
        int x = (t >= off) ? sm[t - off] : 0;
        __syncthreads();
        sm[t] += x;
        __syncthreads();
    }
    if (t < NB) partials[t] = sm[t] - v;  // exclusive
    if (t == 127) partials[NB] = sm[127]; // total
}

__global__ void scan3_kernel(int* __restrict__ row_ptr, const int* __restrict__ partials,
                             int N, int NB) {
    int g = blockIdx.x * SCAN_BLK + threadIdx.x;
    if (g < N) row_ptr[g] += partials[blockIdx.x];
    if (blockIdx.x == 0 && threadIdx.x == 0) row_ptr[N] = partials[NB];
}

// atomic-free scatter using precomputed ranks; non-temporal stores
__global__ void scatter_kernel(const int* __restrict__ src, const int* __restrict__ dst,
                               const float* __restrict__ ef, const int* __restrict__ row_ptr,
                               const int* __restrict__ rank, int2* __restrict__ erec, int E) {
    int tid = blockIdx.x * blockDim.x + threadIdx.x;
    if (tid >= E) return;
    int d = dst[tid];
    int pos = row_ptr[d] + rank[tid];
    union { int2 r; long long ll; } u;
    u.r.x = src[tid];
    u.r.y = __float_as_int(ef[tid]);
    __builtin_nontemporal_store(u.ll, (long long*)&erec[pos]);
}

// ---------------------------------------------------------------- node projection
// RECB>0: write packed per-node record (ft 3 heads + el 3 floats) of RECB bytes.
// RECB==0: write ft [N,3,D] fp16 + el array (el stays L2-resident separately).
template <int FIN, int D, int RECB>
__launch_bounds__(256)
__global__ void node_kernel(const float* __restrict__ xin,   // [N,FIN]
                            const float* __restrict__ W,
                            const float* __restrict__ al,
                            const float* __restrict__ ar,
                            char* __restrict__ rec,          // packed (RECB>0)
                            __half* __restrict__ ft,         // plain (RECB==0)
                            float* __restrict__ el, float* __restrict__ er,
                            int N) {
    int tid = blockIdx.x * blockDim.x + threadIdx.x;
    if (tid >= N * HEADS) return;
    int n = tid / HEADS, h = tid % HEADS;
    float x[FIN];
    #pragma unroll
    for (int k = 0; k < FIN; k++) x[k] = xin[n * FIN + k];
    float fv[D];
    float e_l = 0.f, e_r = 0.f;
    #pragma unroll
    for (int d = 0; d < D; d++) {
        const float* wr = &W[(h * D + d) * FIN];
        float f = 0.f;
        #pragma unroll
        for (int k = 0; k < FIN; k++) f += x[k] * wr[k];
        fv[d] = f;
        e_l += f * al[h * D + d];
        e_r += f * ar[h * D + d];
    }
    if (RECB > 0) {
        char* rp = rec + (size_t)n * RECB;
        uint4* dst16 = (uint4*)(rp + h * (D * 2));
        #pragma unroll
        for (int q = 0; q < D / 8; q++) {
            HU u;
            #pragma unroll
            for (int j = 0; j < 4; j++)
                u.h[j] = __floats2half2_rn(fv[q * 8 + 2 * j], fv[q * 8 + 2 * j + 1]);
            dst16[q] = u.u;
        }
        *(float*)(rp + 3 * D * 2 + h * 4) = e_l;
    } else {
        uint4* dst16 = (uint4*)(ft + (size_t)tid * D);
        #pragma unroll
        for (int q = 0; q < D / 8; q++) {
            HU u;
            #pragma unroll
            for (int j = 0; j < 4; j++)
                u.h[j] = __floats2half2_rn(fv[q * 8 + 2 * j], fv[q * 8 + 2 * j + 1]);
            dst16[q] = u.u;
        }
        el[tid] = e_l;
    }
    er[tid] = e_r;
}

// ---------------------------------------------------------------- attention + aggregate
// 6 lanes per node: (slice s in {0,1}) x (head h in {0,1,2}); 10 nodes per wave.
// BLOCK-LOCAL degree sort: each block sorts its 40-node window by degree in LDS
// and assigns similar-degree nodes to the same wave (kills intra-wave stragglers
// without destroying locality -- node ids stay inside the 40-node window).
// RECB>0: gather packed record (1 line/edge, layer 1). RECB==0: ft + L2-resident el.
// EPI==0: epilogue writes head-mean xmean. EPI==1: writes fp16 h3 row.
template <int D, int RECB, int EPI>
__launch_bounds__(256)
__global__ void agg_kernel(const int* __restrict__ row_ptr, const int2* __restrict__ erec,
                           const char* __restrict__ rec,
                           const __half* __restrict__ ft,
                           const float* __restrict__ el, const float* __restrict__ er,
                           const float* __restrict__ ce,   // [3] this layer
                           const float* __restrict__ b,    // [3*D]
                           float* __restrict__ xmean,      // [N,D]   (EPI==0)
                           __half* __restrict__ h3out,     // [N,3,D] (EPI==1)
                           int N) {
    const int ELOFF = 3 * D * 2;
    __shared__ int dsh[40];
    __shared__ int ordsh[40];
    int nb = blockIdx.x * 40;
    {
        int t = threadIdx.x;
        if (t < 40) {
            int nn = nb + t;
            dsh[t] = (nn < N) ? (row_ptr[nn + 1] - row_ptr[nn]) : 0x3fffffff;
        }
        __syncthreads();
        if (t < 40) {
            int dt = dsh[t];
            int r = 0;
            #pragma unroll 8
            for (int j = 0; j < 40; j++) {
                int dj = dsh[j];
                r += (dj < dt) || (dj == dt && j < t);
            }
            ordsh[r] = t;
        }
        __syncthreads();
    }

    int w = threadIdx.x >> 6;
    int l = threadIdx.x & 63;
    int wl = l / 6;                 // node slot within wave, 0..9 (l>=60 idle)
    int rem = l - wl * 6;
    int s = rem >= 3 ? 1 : 0;
    int h = rem - s * 3;
    int n = (wl < 10) ? nb + ordsh[w * 10 + wl] : N;
    bool active = (wl < 10) && (n < N);
    if (!active) n = 0;

    float m = -3.0e38f, ssum = 0.f;
    float msg[D];
    #pragma unroll
    for (int d = 0; d < D; d++) msg[d] = 0.f;
    int unit = n * HEADS + h;
    float ceh = ce[h];

    if (active) {
        int beg = row_ptr[n], end = row_ptr[n + 1];
        int cnt = end - beg;
        int half = (cnt + 1) >> 1;
        int es = beg + s * half;
        int ee = s ? end : (beg + half);
        float ern = er[unit];

        int e = es;
        for (; e + 3 < ee; e += 4) {
            int2 r0 = erec[e + 0], r1 = erec[e + 1], r2 = erec[e + 2], r3 = erec[e + 3];
            const char* p0; const char* p1; const char* p2; const char* p3;
            float v0, v1, v2, v3;
            if (RECB > 0) {
                p0 = rec + (size_t)r0.x * RECB; p1 = rec + (size_t)r1.x * RECB;
                p2 = rec + (size_t)r2.x * RECB; p3 = rec + (size_t)r3.x * RECB;
                v0 = *(const float*)(p0 + ELOFF + h * 4) + ern + __int_as_float(r0.y) * ceh;
                v1 = *(const float*)(p1 + ELOFF + h * 4) + ern + __int_as_float(r1.y) * ceh;
                v2 = *(const float*)(p2 + ELOFF + h * 4) + ern + __int_as_float(r2.y) * ceh;
                v3 = *(const float*)(p3 + ELOFF + h * 4) + ern + __int_as_float(r3.y) * ceh;
            } else {
                p0 = (const char*)(ft + ((size_t)r0.x * HEADS + h) * D);
                p1 = (const char*)(ft + ((size_t)r1.x * HEADS + h) * D);
                p2 = (const char*)(ft + ((size_t)r2.x * HEADS + h) * D);
                p3 = (const char*)(ft + ((size_t)r3.x * HEADS + h) * D);
                v0 = el[r0.x * HEADS + h] + ern + __int_as_float(r0.y) * ceh;
                v1 = el[r1.x * HEADS + h] + ern + __int_as_float(r1.y) * ceh;
                v2 = el[r2.x * HEADS + h] + ern + __int_as_float(r2.y) * ceh;
                v3 = el[r3.x * HEADS + h] + ern + __int_as_float(r3.y) * ceh;
            }
            v0 = v0 > 0.f ? v0 : 0.2f * v0;
            v1 = v1 > 0.f ? v1 : 0.2f * v1;
            v2 = v2 > 0.f ? v2 : 0.2f * v2;
            v3 = v3 > 0.f ? v3 : 0.2f * v3;
            float cm = fmaxf(fmaxf(v0, v1), fmaxf(v2, v3));
            if (cm > m) {
                float sc = __expf(m - cm);
                ssum *= sc;
                #pragma unroll
                for (int d = 0; d < D; d++) msg[d] *= sc;
                m = cm;
            }
            float x0 = __expf(v0 - m), x1 = __expf(v1 - m);
            float x2 = __expf(v2 - m), x3 = __expf(v3 - m);
            ssum += (x0 + x1) + (x2 + x3);
            const uint4* f0 = (const uint4*)(RECB > 0 ? p0 + h * (D * 2) : p0);
            const uint4* f1 = (const uint4*)(RECB > 0 ? p1 + h * (D * 2) : p1);
            const uint4* f2 = (const uint4*)(RECB > 0 ? p2 + h * (D * 2) : p2);
            const uint4* f3 = (const uint4*)(RECB > 0 ? p3 + h * (D * 2) : p3);
            #pragma unroll
            for (int q = 0; q < D / 8; q++) {
                HU a0, a1, a2, a3;
                a0.u = f0[q]; a1.u = f1[q]; a2.u = f2[q]; a3.u = f3[q];
                #pragma unroll
                for (int j = 0; j < 4; j++) {
                    float2 p0v = __half22float2(a0.h[j]);
                    float2 p1v = __half22float2(a1.h[j]);
                    float2 p2v = __half22float2(a2.h[j]);
                    float2 p3v = __half22float2(a3.h[j]);
                    msg[q * 8 + 2 * j + 0] += x0 * p0v.x + x1 * p1v.x + x2 * p2v.x + x3 * p3v.x;
                    msg[q * 8 + 2 * j + 1] += x0 * p0v.y + x1 * p1v.y + x2 * p2v.y + x3 * p3v.y;
                }
            }
        }
        for (; e < ee; e++) {
            int2 r = erec[e];
            const char* pr;
            float v;
            if (RECB > 0) {
                pr = rec + (size_t)r.x * RECB;
                v = *(const float*)(pr + ELOFF + h * 4) + ern + __int_as_float(r.y) * ceh;
            } else {
                pr = (const char*)(ft + ((size_t)r.x * HEADS + h) * D);
                v = el[r.x * HEADS + h] + ern + __int_as_float(r.y) * ceh;
            }
            v = v > 0.f ? v : 0.2f * v;
            if (v > m) {
                float sc = __expf(m - v);
                ssum *= sc;
                #pragma unroll
                for (int d = 0; d < D; d++) msg[d] *= sc;
                m = v;
            }
            float x = __expf(v - m);
            ssum += x;
            const uint4* fr = (const uint4*)(RECB > 0 ? pr + h * (D * 2) : pr);
            #pragma unroll
            for (int q = 0; q < D / 8; q++) {
                HU a; a.u = fr[q];
                #pragma unroll
                for (int j = 0; j < 4; j++) {
                    float2 p = __half22float2(a.h[j]);
                    msg[q * 8 + 2 * j + 0] += x * p.x;
                    msg[q * 8 + 2 * j + 1] += x * p.y;
                }
            }
        }
    }

    // slice-pair combine: partner lane at +/-3 (other slice, same head), in-place
    int pl = (s ? (l - 3) : (l + 3)) & 63;
    float om = __shfl(m, pl);
    float osum = __shfl(ssum, pl);
    float M = fmaxf(m, om);
    float sA = __expf(m - M);
    float sB = __expf(om - M);
    float tot = ssum * sA + osum * sB;
    float inv = 1.0f / fmaxf(tot, 1e-9f);
    #pragma unroll
    for (int d = 0; d < D; d++)
        msg[d] = (msg[d] * sA + __shfl(msg[d], pl) * sB) * inv + b[h * D + d];
    // both slices now hold the identical full output row msg[0..D)

    if (EPI == 0) {
        // head-mean fused: mean over the 3 h-lanes of this (node, slice)
        int g0 = (l / 6) * 6 + s * 3;
        int g0w = (threadIdx.x & ~63) ? 0 : 0;  // (quiet unused warning path)
        (void)g0w;
        #pragma unroll
        for (int d = 0; d < D; d++)
            msg[d] = (__shfl(msg[d], g0) + __shfl(msg[d], g0 + 1) + __shfl(msg[d], g0 + 2)) * (1.0f / 3.0f);
        if (active && h == 0) {
            int lo = s * (D / 2);
            float* ob = xmean + (size_t)n * D + lo;
            #pragma unroll
            for (int d = 0; d < D / 2; d += 4) {
                float4 v;
                v.x = msg[lo + d + 0]; v.y = msg[lo + d + 1];
                v.z = msg[lo + d + 2]; v.w = msg[lo + d + 3];
                *(float4*)(ob + d) = v;
            }
        }
    } else {
        // write this (n,h) row as fp16; slice s writes its half [lo, lo+D/2)
        if (active) {
            int lo = s * (D / 2);
            __half* hb = h3out + ((size_t)n * HEADS + h) * D + lo;
            #pragma unroll
            for (int q = 0; q < D / 16; q++) {    // D=32: 2 x 8-half chunks per slice
                HU u;
                #pragma unroll
                for (int j = 0; j < 4; j++)
                    u.h[j] = __floats2half2_rn(msg[lo + q * 8 + 2 * j],
                                               msg[lo + q * 8 + 2 * j + 1]);
                *(uint4*)(hb + q * 8) = u.u;
            }
        }
    }
}

// ---------------------------------------------------------------- MLP head + global max (fp16 input)
__global__ void mlp_max_kernel(const __half* __restrict__ h3,   // [N,3,32] fp16
                               const float* __restrict__ l1w, const float* __restrict__ l1b,
                               const float* __restrict__ l2w, const float* __restrict__ l2b,
                               const float* __restrict__ l3w, const float* __restrict__ l3b,
                               const float* __restrict__ l4w, const float* __restrict__ l4b,
                               unsigned int* __restrict__ maxkey, int N) {
    int tid = blockIdx.x * blockDim.x + threadIdx.x;
    float feat = -3.0e38f;
    if (tid < N) {
        float acc = l4b[0];
        #pragma unroll
        for (int h = 0; h < HEADS; h++) {
            const uint4* vp = (const uint4*)(h3 + ((size_t)tid * HEADS + h) * 32);
            float v[32];
            #pragma unroll
            for (int q = 0; q < 4; q++) {
                HU a; a.u = vp[q];
                #pragma unroll
                for (int j = 0; j < 4; j++) {
                    float2 p = __half22float2(a.h[j]);
                    v[q * 8 + 2 * j + 0] = p.x;
                    v[q * 8 + 2 * j + 1] = p.y;
                }
            }
            float y1[16];
            #pragma unroll
            for (int i = 0; i < 16; i++) {
                float s = l1b[i];
                const float* w = &l1w[i * 32];
                #pragma unroll
                for (int k = 0; k < 32; k++) s += v[k] * w[k];
                y1[i] = s > 0.f ? s : 0.01f * s;
            }
            float y2[4];
            #pragma unroll
            for (int i = 0; i < 4; i++) {
                float s = l2b[i];
                const float* w = &l2w[i * 16];
                #pragma unroll
                for (int k = 0; k < 16; k++) s += y1[k] * w[k];
                y2[i] = s > 0.f ? s : 0.01f * s;
            }
            float y3 = l3b[0];
            #pragma unroll
            for (int k = 0; k < 4; k++) y3 += y2[k] * l3w[k];
            acc += y3 * l4w[h];
        }
        feat = acc;
    }
    #pragma unroll
    for (int off = 32; off > 0; off >>= 1)
        feat = fmaxf(feat, __shfl_down(feat, off));
    if ((threadIdx.x & 63) == 0) {
        unsigned int u = __float_as_uint(feat);
        unsigned int key = (u & 0x80000000u) ? ~u : (u | 0x80000000u);
        atomicMax(maxkey, key);
    }
}

__global__ void finalize_kernel(const unsigned int* __restrict__ maxkey, float* __restrict__ out) {
    unsigned int key = *maxkey;
    unsigned int u = (key & 0x80000000u) ? (key & 0x7FFFFFFFu) : ~key;
    out[0] = __uint_as_float(u);
}

// ----------------------------------------------------------------
extern "C" void kernel_launch(void* const* d_in, const int* in_sizes, int n_in,
                              void* d_out, int out_size, void* d_ws, size_t ws_size,
                              hipStream_t stream) {
    const float* node_feats = (const float*)d_in[0];
    const float* edge_feats = (const float*)d_in[1];
    const int* src = (const int*)d_in[2];
    const int* dst = (const int*)d_in[3];
    const float* W1  = (const float*)d_in[4];
    const float* We1 = (const float*)d_in[5];
    const float* al1 = (const float*)d_in[6];
    const float* ar1 = (const float*)d_in[7];
    const float* ae1 = (const float*)d_in[8];
    const float* b1  = (const float*)d_in[9];
    const float* W2  = (const float*)d_in[10];
    const float* We2 = (const float*)d_in[11];
    const float* al2 = (const float*)d_in[12];
    const float* ar2 = (const float*)d_in[13];
    const float* ae2 = (const float*)d_in[14];
    const float* b2  = (const float*)d_in[15];
    const float* W3  = (const float*)d_in[16];
    const float* We3 = (const float*)d_in[17];
    const float* al3 = (const float*)d_in[18];
    const float* ar3 = (const float*)d_in[19];
    const float* ae3 = (const float*)d_in[20];
    const float* b3  = (const float*)d_in[21];
    const float* l1w = (const float*)d_in[22];
    const float* l1b = (const float*)d_in[23];
    const float* l2w = (const float*)d_in[24];
    const float* l2b = (const float*)d_in[25];
    const float* l3w = (const float*)d_in[26];
    const float* l3b = (const float*)d_in[27];
    const float* l4w = (const float*)d_in[28];
    const float* l4b = (const float*)d_in[29];

    const int N = in_sizes[0] / 6;
    const int E = in_sizes[2];
    const int NB = (N + SCAN_BLK - 1) / SCAN_BLK;

    char* ws = (char*)d_ws;
    size_t off = 0;
    auto alloc = [&](size_t bytes) -> void* {
        void* p = ws + off;
        off = (off + bytes + 255) & ~(size_t)255;
        return p;
    };
    int* deg            = (int*)alloc((size_t)N * 4);
    unsigned int* mkey  = (unsigned int*)alloc(4);
    size_t zero_bytes   = off;  // deg + maxkey
    int* rank           = (int*)alloc((size_t)E * 4);
    int* row_ptr        = (int*)alloc((size_t)(N + 1) * 4);
    int* partials       = (int*)alloc((size_t)(NB + 1) * 4);
    int2* erec          = (int2*)alloc((size_t)E * 8);
    char* rec1          = (char*)alloc((size_t)N * 64);       // layer-1 packed records
    __half* ft          = (__half*)alloc((size_t)N * 96 * 2);
    __half* h3          = (__half*)alloc((size_t)N * 96 * 2);
    float* xmean        = (float*)alloc((size_t)N * 16 * 4);  // up to D=16
    float* el           = (float*)alloc((size_t)N * 3 * 4);
    float* er           = (float*)alloc((size_t)N * 3 * 4);
    float* ce           = (float*)alloc(9 * 4);

    hipMemsetAsync(d_ws, 0, zero_bytes, stream);

    prep_ce_kernel<<<1, 16, 0, stream>>>(We1, ae1, We2, ae2, We3, ae3, ce);
    hist_rank_kernel<<<(E + 255) / 256, 256, 0, stream>>>(dst, deg, rank, E);
    scan1_kernel<<<NB, SCAN_BLK, 0, stream>>>(deg, row_ptr, partials, N);
    scan2_kernel<<<1, 128, 0, stream>>>(partials, NB);
    scan3_kernel<<<NB, SCAN_BLK, 0, stream>>>(row_ptr, partials, N, NB);
    scatter_kernel<<<(E + 255) / 256, 256, 0, stream>>>(src, dst, edge_feats, row_ptr, rank,
                                                        erec, E);

    const int NH = N * HEADS;
    const int gb = (NH + 255) / 256;
    const int gb_agg = (N + 39) / 40;   // 40 nodes per 256-thread block

    // layer 1: 6 -> 8, packed 64B records (1 line/edge gathers)
    node_kernel<6, 8, 64><<<gb, 256, 0, stream>>>(node_feats, W1, al1, ar1, rec1, nullptr,
                                                  nullptr, er, N);
    agg_kernel<8, 64, 0><<<gb_agg, 256, 0, stream>>>(row_ptr, erec, rec1, nullptr,
                                                     nullptr, er, ce + 0, b1, xmean, nullptr, N);
    // layer 2: 8 -> 16
    node_kernel<8, 16, 0><<<gb, 256, 0, stream>>>(xmean, W2, al2, ar2, nullptr, ft, el, er, N);
    agg_kernel<16, 0, 0><<<gb_agg, 256, 0, stream>>>(row_ptr, erec, nullptr, ft,
                                                     el, er, ce + 3, b2, xmean, nullptr, N);
    // layer 3: 16 -> 32, epilogue writes fp16 h3
    node_kernel<16, 32, 0><<<gb, 256, 0, stream>>>(xmean, W3, al3, ar3, nullptr, ft, el, er, N);
    agg_kernel<32, 0, 1><<<gb_agg, 256, 0, stream>>>(row_ptr, erec, nullptr, ft,
                                                     el, er, ce + 6, b3, nullptr, h3, N);

    // MLP head + global max (fp16 h3)
    mlp_max_kernel<<<(N + 255) / 256, 256, 0, stream>>>(h3, l1w, l1b, l2w, l2b, l3w, l3b,
                                                        l4w, l4b, mkey, N);
    finalize_kernel<<<1, 1, 0, stream>>>(mkey, (float*)d_out);
}

// Round 14
// 458.820 us; speedup vs baseline: 1.0215x; 1.0215x over previous
//
#include <hip/hip_runtime.h>
#include <hip/hip_bf16.h>
#include <hip/hip_fp16.h>

#define HEADS 3

union HU { uint4 u; __half2 h[4]; };

// ---------------------------------------------------------------- prep: ce[h] = sum_d We[h*D+d] * ae[h*D+d]
__global__ void prep_ce_kernel(const float* __restrict__ We1, const float* __restrict__ ae1,
                               const float* __restrict__ We2, const float* __restrict__ ae2,
                               const float* __restrict__ We3, const float* __restrict__ ae3,
                               float* __restrict__ ce) {
    int t = threadIdx.x;
    if (t >= 9) return;
    int l = t / 3, h = t % 3;
    const float* We = (l == 0) ? We1 : (l == 1) ? We2 : We3;
    const float* ae = (l == 0) ? ae1 : (l == 1) ? ae2 : ae3;
    int D = (l == 0) ? 8 : (l == 1) ? 16 : 32;
    float s = 0.f;
    for (int d = 0; d < D; d++) s += We[h * D + d] * ae[h * D + d];
    ce[t] = s;
}

// ---------------------------------------------------------------- CSR build
__global__ void hist_rank_kernel(const int* __restrict__ dst, int* __restrict__ deg,
                                 int* __restrict__ rank, int E) {
    int tid = blockIdx.x * blockDim.x + threadIdx.x;
    if (tid < E) {
        int r = atomicAdd(&deg[dst[tid]], 1);
        __builtin_nontemporal_store(r, &rank[tid]);
    }
}

#define SCAN_BLK 1024
__global__ void scan1_kernel(const int* __restrict__ deg, int* __restrict__ row_ptr,
                             int* __restrict__ partials, int N) {
    __shared__ int sm[SCAN_BLK];
    int t = threadIdx.x;
    int g = blockIdx.x * SCAN_BLK + t;
    int v = (g < N) ? deg[g] : 0;
    sm[t] = v;
    __syncthreads();
    for (int off = 1; off < SCAN_BLK; off <<= 1) {
        int x = (t >= off) ? sm[t - off] : 0;
        __syncthreads();
        sm[t] += x;
        __syncthreads();
    }
    if (g < N) row_ptr[g] = sm[t] - v;   // exclusive
    if (t == SCAN_BLK - 1) partials[blockIdx.x] = sm[t];
}

__global__ void scan2_kernel(int* __restrict__ partials, int NB) {
    __shared__ int sm[128];
    int t = threadIdx.x;
    int v = (t < NB) ? partials[t] : 0;
    sm[t] = v;
    __syncthreads();
    for (int off = 1; off < 128; off <<= 1) {
        int x = (t >= off) ? sm[t - off] : 0;
        __syncthreads();
        sm[t] += x;
        __syncthreads();
    }
    if (t < NB) partials[t] = sm[t] - v;  // exclusive
    if (t == 127) partials[NB] = sm[127]; // total
}

__global__ void scan3_kernel(int* __restrict__ row_ptr, const int* __restrict__ partials,
                             int N, int NB) {
    int g = blockIdx.x * SCAN_BLK + threadIdx.x;
    if (g < N) row_ptr[g] += partials[blockIdx.x];
    if (blockIdx.x == 0 && threadIdx.x == 0) row_ptr[N] = partials[NB];
}

// atomic-free scatter using precomputed ranks; non-temporal stores
__global__ void scatter_kernel(const int* __restrict__ src, const int* __restrict__ dst,
                               const float* __restrict__ ef, const int* __restrict__ row_ptr,
                               const int* __restrict__ rank, int2* __restrict__ erec, int E) {
    int tid = blockIdx.x * blockDim.x + threadIdx.x;
    if (tid >= E) return;
    int d = dst[tid];
    int pos = row_ptr[d] + rank[tid];
    union { int2 r; long long ll; } u;
    u.r.x = src[tid];
    u.r.y = __float_as_int(ef[tid]);
    __builtin_nontemporal_store(u.ll, (long long*)&erec[pos]);
}

// ---------------------------------------------------------------- node projection
// RECB>0: write packed per-node record (ft 3 heads + el 3 floats) of RECB bytes.
// RECB==0: write ft [N,3,D] fp16 + el array (el stays L2-resident separately).
template <int FIN, int D, int RECB>
__launch_bounds__(256)
__global__ void node_kernel(const float* __restrict__ xin,   // [N,FIN]
                            const float* __restrict__ W,
                            const float* __restrict__ al,
                            const float* __restrict__ ar,
                            char* __restrict__ rec,          // packed (RECB>0)
                            __half* __restrict__ ft,         // plain (RECB==0)
                            float* __restrict__ el, float* __restrict__ er,
                            int N) {
    int tid = blockIdx.x * blockDim.x + threadIdx.x;
    if (tid >= N * HEADS) return;
    int n = tid / HEADS, h = tid % HEADS;
    float x[FIN];
    #pragma unroll
    for (int k = 0; k < FIN; k++) x[k] = xin[n * FIN + k];
    float fv[D];
    float e_l = 0.f, e_r = 0.f;
    #pragma unroll
    for (int d = 0; d < D; d++) {
        const float* wr = &W[(h * D + d) * FIN];
        float f = 0.f;
        #pragma unroll
        for (int k = 0; k < FIN; k++) f += x[k] * wr[k];
        fv[d] = f;
        e_l += f * al[h * D + d];
        e_r += f * ar[h * D + d];
    }
    if (RECB > 0) {
        char* rp = rec + (size_t)n * RECB;
        uint4* dst16 = (uint4*)(rp + h * (D * 2));
        #pragma unroll
        for (int q = 0; q < D / 8; q++) {
            HU u;
            #pragma unroll
            for (int j = 0; j < 4; j++)
                u.h[j] = __floats2half2_rn(fv[q * 8 + 2 * j], fv[q * 8 + 2 * j + 1]);
            dst16[q] = u.u;
        }
        *(float*)(rp + 3 * D * 2 + h * 4) = e_l;
    } else {
        uint4* dst16 = (uint4*)(ft + (size_t)tid * D);
        #pragma unroll
        for (int q = 0; q < D / 8; q++) {
            HU u;
            #pragma unroll
            for (int j = 0; j < 4; j++)
                u.h[j] = __floats2half2_rn(fv[q * 8 + 2 * j], fv[q * 8 + 2 * j + 1]);
            dst16[q] = u.u;
        }
        el[tid] = e_l;
    }
    er[tid] = e_r;
}

// ---------------------------------------------------------------- attention + aggregate
// 6 lanes per node: (slice s in {0,1}) x (head h in {0,1,2}); 10 nodes per wave,
// sequential node ids (coalesced er/row_ptr/output).
// RECB>0: gather packed record (1 line/edge for layer 1). RECB==0: ft + L2-resident el.
// EPI==0: epilogue writes head-mean xmean. EPI==1: writes fp16 h3 row.
template <int D, int RECB, int EPI>
__launch_bounds__(256)
__global__ void agg_kernel(const int* __restrict__ row_ptr, const int2* __restrict__ erec,
                           const char* __restrict__ rec,
                           const __half* __restrict__ ft,
                           const float* __restrict__ el, const float* __restrict__ er,
                           const float* __restrict__ ce,   // [3] this layer
                           const float* __restrict__ b,    // [3*D]
                           float* __restrict__ xmean,      // [N,D]   (EPI==0)
                           __half* __restrict__ h3out,     // [N,3,D] (EPI==1)
                           int N) {
    const int ELOFF = 3 * D * 2;
    int w = threadIdx.x >> 6;
    int l = threadIdx.x & 63;
    int wl = l / 6;                 // node slot within wave, 0..9 (l>=60 idle)
    int rem = l - wl * 6;
    int s = rem >= 3 ? 1 : 0;
    int h = rem - s * 3;
    int n = (blockIdx.x * 4 + w) * 10 + wl;
    bool active = (wl < 10) && (n < N);

    float m = -3.0e38f, ssum = 0.f;
    float msg[D];
    #pragma unroll
    for (int d = 0; d < D; d++) msg[d] = 0.f;
    int unit = n * HEADS + h;
    float ceh = ce[h];

    if (active) {
        int beg = row_ptr[n], end = row_ptr[n + 1];
        int cnt = end - beg;
        int half = (cnt + 1) >> 1;
        int es = beg + s * half;
        int ee = s ? end : (beg + half);
        float ern = er[unit];

        int e = es;
        for (; e + 3 < ee; e += 4) {
            int2 r0 = erec[e + 0], r1 = erec[e + 1], r2 = erec[e + 2], r3 = erec[e + 3];
            const char* p0; const char* p1; const char* p2; const char* p3;
            float v0, v1, v2, v3;
            if (RECB > 0) {
                p0 = rec + (size_t)r0.x * RECB; p1 = rec + (size_t)r1.x * RECB;
                p2 = rec + (size_t)r2.x * RECB; p3 = rec + (size_t)r3.x * RECB;
                v0 = *(const float*)(p0 + ELOFF + h * 4) + ern + __int_as_float(r0.y) * ceh;
                v1 = *(const float*)(p1 + ELOFF + h * 4) + ern + __int_as_float(r1.y) * ceh;
                v2 = *(const float*)(p2 + ELOFF + h * 4) + ern + __int_as_float(r2.y) * ceh;
                v3 = *(const float*)(p3 + ELOFF + h * 4) + ern + __int_as_float(r3.y) * ceh;
            } else {
                p0 = (const char*)(ft + ((size_t)r0.x * HEADS + h) * D);
                p1 = (const char*)(ft + ((size_t)r1.x * HEADS + h) * D);
                p2 = (const char*)(ft + ((size_t)r2.x * HEADS + h) * D);
                p3 = (const char*)(ft + ((size_t)r3.x * HEADS + h) * D);
                v0 = el[r0.x * HEADS + h] + ern + __int_as_float(r0.y) * ceh;
                v1 = el[r1.x * HEADS + h] + ern + __int_as_float(r1.y) * ceh;
                v2 = el[r2.x * HEADS + h] + ern + __int_as_float(r2.y) * ceh;
                v3 = el[r3.x * HEADS + h] + ern + __int_as_float(r3.y) * ceh;
            }
            v0 = v0 > 0.f ? v0 : 0.2f * v0;
            v1 = v1 > 0.f ? v1 : 0.2f * v1;
            v2 = v2 > 0.f ? v2 : 0.2f * v2;
            v3 = v3 > 0.f ? v3 : 0.2f * v3;
            float cm = fmaxf(fmaxf(v0, v1), fmaxf(v2, v3));
            if (cm > m) {
                float sc = __expf(m - cm);
                ssum *= sc;
                #pragma unroll
                for (int d = 0; d < D; d++) msg[d] *= sc;
                m = cm;
            }
            float x0 = __expf(v0 - m), x1 = __expf(v1 - m);
            float x2 = __expf(v2 - m), x3 = __expf(v3 - m);
            ssum += (x0 + x1) + (x2 + x3);
            const uint4* f0 = (const uint4*)(RECB > 0 ? p0 + h * (D * 2) : p0);
            const uint4* f1 = (const uint4*)(RECB > 0 ? p1 + h * (D * 2) : p1);
            const uint4* f2 = (const uint4*)(RECB > 0 ? p2 + h * (D * 2) : p2);
            const uint4* f3 = (const uint4*)(RECB > 0 ? p3 + h * (D * 2) : p3);
            #pragma unroll
            for (int q = 0; q < D / 8; q++) {
                HU a0, a1, a2, a3;
                a0.u = f0[q]; a1.u = f1[q]; a2.u = f2[q]; a3.u = f3[q];
                #pragma unroll
                for (int j = 0; j < 4; j++) {
                    float2 p0v = __half22float2(a0.h[j]);
                    float2 p1v = __half22float2(a1.h[j]);
                    float2 p2v = __half22float2(a2.h[j]);
                    float2 p3v = __half22float2(a3.h[j]);
                    msg[q * 8 + 2 * j + 0] += x0 * p0v.x + x1 * p1v.x + x2 * p2v.x + x3 * p3v.x;
                    msg[q * 8 + 2 * j + 1] += x0 * p0v.y + x1 * p1v.y + x2 * p2v.y + x3 * p3v.y;
                }
            }
        }
        for (; e < ee; e++) {
            int2 r = erec[e];
            const char* pr;
            float v;
            if (RECB > 0) {
                pr = rec + (size_t)r.x * RECB;
                v = *(const float*)(pr + ELOFF + h * 4) + ern + __int_as_float(r.y) * ceh;
            } else {
                pr = (const char*)(ft + ((size_t)r.x * HEADS + h) * D);
                v = el[r.x * HEADS + h] + ern + __int_as_float(r.y) * ceh;
            }
            v = v > 0.f ? v : 0.2f * v;
            if (v > m) {
                float sc = __expf(m - v);
                ssum *= sc;
                #pragma unroll
                for (int d = 0; d < D; d++) msg[d] *= sc;
                m = v;
            }
            float x = __expf(v - m);
            ssum += x;
            const uint4* fr = (const uint4*)(RECB > 0 ? pr + h * (D * 2) : pr);
            #pragma unroll
            for (int q = 0; q < D / 8; q++) {
                HU a; a.u = fr[q];
                #pragma unroll
                for (int j = 0; j < 4; j++) {
                    float2 p = __half22float2(a.h[j]);
                    msg[q * 8 + 2 * j + 0] += x * p.x;
                    msg[q * 8 + 2 * j + 1] += x * p.y;
                }
            }
        }
    }

    // slice-pair combine: partner lane at +/-3 (other slice, same head), in-place
    int pl = (s ? (l - 3) : (l + 3)) & 63;
    float om = __shfl(m, pl);
    float osum = __shfl(ssum, pl);
    float M = fmaxf(m, om);
    float sA = __expf(m - M);
    float sB = __expf(om - M);
    float tot = ssum * sA + osum * sB;
    float inv = 1.0f / fmaxf(tot, 1e-9f);
    #pragma unroll
    for (int d = 0; d < D; d++)
        msg[d] = (msg[d] * sA + __shfl(msg[d], pl) * sB) * inv + b[h * D + d];
    // both slices now hold the identical full output row msg[0..D)

    if (EPI == 0) {
        // head-mean fused: mean over the 3 h-lanes of this (node, slice)
        int g0 = wl * 6 + s * 3;
        #pragma unroll
        for (int d = 0; d < D; d++)
            msg[d] = (__shfl(msg[d], g0) + __shfl(msg[d], g0 + 1) + __shfl(msg[d], g0 + 2)) * (1.0f / 3.0f);
        if (active && h == 0) {
            int lo = s * (D / 2);
            float* ob = xmean + (size_t)n * D + lo;
            #pragma unroll
            for (int d = 0; d < D / 2; d += 4) {
                float4 v;
                v.x = msg[lo + d + 0]; v.y = msg[lo + d + 1];
                v.z = msg[lo + d + 2]; v.w = msg[lo + d + 3];
                *(float4*)(ob + d) = v;
            }
        }
    } else {
        // write this (n,h) row as fp16; slice s writes its half [lo, lo+D/2)
        if (active) {
            int lo = s * (D / 2);
            __half* hb = h3out + ((size_t)n * HEADS + h) * D + lo;
            #pragma unroll
            for (int q = 0; q < D / 16; q++) {    // D=32: 2 x 8-half chunks per slice
                HU u;
                #pragma unroll
                for (int j = 0; j < 4; j++)
                    u.h[j] = __floats2half2_rn(msg[lo + q * 8 + 2 * j],
                                               msg[lo + q * 8 + 2 * j + 1]);
                *(uint4*)(hb + q * 8) = u.u;
            }
        }
    }
}

// ---------------------------------------------------------------- MLP head + global max (fp16 input)
__global__ void mlp_max_kernel(const __half* __restrict__ h3,   // [N,3,32] fp16
                               const float* __restrict__ l1w, const float* __restrict__ l1b,
                               const float* __restrict__ l2w, const float* __restrict__ l2b,
                               const float* __restrict__ l3w, const float* __restrict__ l3b,
                               const float* __restrict__ l4w, const float* __restrict__ l4b,
                               unsigned int* __restrict__ maxkey, int N) {
    int tid = blockIdx.x * blockDim.x + threadIdx.x;
    float feat = -3.0e38f;
    if (tid < N) {
        float acc = l4b[0];
        #pragma unroll
        for (int h = 0; h < HEADS; h++) {
            const uint4* vp = (const uint4*)(h3 + ((size_t)tid * HEADS + h) * 32);
            float v[32];
            #pragma unroll
            for (int q = 0; q < 4; q++) {
                HU a; a.u = vp[q];
                #pragma unroll
                for (int j = 0; j < 4; j++) {
                    float2 p = __half22float2(a.h[j]);
                    v[q * 8 + 2 * j + 0] = p.x;
                    v[q * 8 + 2 * j + 1] = p.y;
                }
            }
            float y1[16];
            #pragma unroll
            for (int i = 0; i < 16; i++) {
                float s = l1b[i];
                const float* w = &l1w[i * 32];
                #pragma unroll
                for (int k = 0; k < 32; k++) s += v[k] * w[k];
                y1[i] = s > 0.f ? s : 0.01f * s;
            }
            float y2[4];
            #pragma unroll
            for (int i = 0; i < 4; i++) {
                float s = l2b[i];
                const float* w = &l2w[i * 16];
                #pragma unroll
                for (int k = 0; k < 16; k++) s += y1[k] * w[k];
                y2[i] = s > 0.f ? s : 0.01f * s;
            }
            float y3 = l3b[0];
            #pragma unroll
            for (int k = 0; k < 4; k++) y3 += y2[k] * l3w[k];
            acc += y3 * l4w[h];
        }
        feat = acc;
    }
    #pragma unroll
    for (int off = 32; off > 0; off >>= 1)
        feat = fmaxf(feat, __shfl_down(feat, off));
    if ((threadIdx.x & 63) == 0) {
        unsigned int u = __float_as_uint(feat);
        unsigned int key = (u & 0x80000000u) ? ~u : (u | 0x80000000u);
        atomicMax(maxkey, key);
    }
}

__global__ void finalize_kernel(const unsigned int* __restrict__ maxkey, float* __restrict__ out) {
    unsigned int key = *maxkey;
    unsigned int u = (key & 0x80000000u) ? (key & 0x7FFFFFFFu) : ~key;
    out[0] = __uint_as_float(u);
}

// ----------------------------------------------------------------
extern "C" void kernel_launch(void* const* d_in, const int* in_sizes, int n_in,
                              void* d_out, int out_size, void* d_ws, size_t ws_size,
                              hipStream_t stream) {
    const float* node_feats = (const float*)d_in[0];
    const float* edge_feats = (const float*)d_in[1];
    const int* src = (const int*)d_in[2];
    const int* dst = (const int*)d_in[3];
    const float* W1  = (const float*)d_in[4];
    const float* We1 = (const float*)d_in[5];
    const float* al1 = (const float*)d_in[6];
    const float* ar1 = (const float*)d_in[7];
    const float* ae1 = (const float*)d_in[8];
    const float* b1  = (const float*)d_in[9];
    const float* W2  = (const float*)d_in[10];
    const float* We2 = (const float*)d_in[11];
    const float* al2 = (const float*)d_in[12];
    const float* ar2 = (const float*)d_in[13];
    const float* ae2 = (const float*)d_in[14];
    const float* b2  = (const float*)d_in[15];
    const float* W3  = (const float*)d_in[16];
    const float* We3 = (const float*)d_in[17];
    const float* al3 = (const float*)d_in[18];
    const float* ar3 = (const float*)d_in[19];
    const float* ae3 = (const float*)d_in[20];
    const float* b3  = (const float*)d_in[21];
    const float* l1w = (const float*)d_in[22];
    const float* l1b = (const float*)d_in[23];
    const float* l2w = (const float*)d_in[24];
    const float* l2b = (const float*)d_in[25];
    const float* l3w = (const float*)d_in[26];
    const float* l3b = (const float*)d_in[27];
    const float* l4w = (const float*)d_in[28];
    const float* l4b = (const float*)d_in[29];

    const int N = in_sizes[0] / 6;
    const int E = in_sizes[2];
    const int NB = (N + SCAN_BLK - 1) / SCAN_BLK;

    char* ws = (char*)d_ws;
    size_t off = 0;
    auto alloc = [&](size_t bytes) -> void* {
        void* p = ws + off;
        off = (off + bytes + 255) & ~(size_t)255;
        return p;
    };
    int* deg            = (int*)alloc((size_t)N * 4);
    unsigned int* mkey  = (unsigned int*)alloc(4);
    size_t zero_bytes   = off;  // deg + maxkey
    int* rank           = (int*)alloc((size_t)E * 4);
    int* row_ptr        = (int*)alloc((size_t)(N + 1) * 4);
    int* partials       = (int*)alloc((size_t)(NB + 1) * 4);
    int2* erec          = (int2*)alloc((size_t)E * 8);
    char* rec1          = (char*)alloc((size_t)N * 64);       // layer-1 packed records
    __half* ft          = (__half*)alloc((size_t)N * 96 * 2);
    __half* h3          = (__half*)alloc((size_t)N * 96 * 2);
    float* xmean        = (float*)alloc((size_t)N * 16 * 4);  // up to D=16
    float* el           = (float*)alloc((size_t)N * 3 * 4);
    float* er           = (float*)alloc((size_t)N * 3 * 4);
    float* ce           = (float*)alloc(9 * 4);

    hipMemsetAsync(d_ws, 0, zero_bytes, stream);

    prep_ce_kernel<<<1, 16, 0, stream>>>(We1, ae1, We2, ae2, We3, ae3, ce);
    hist_rank_kernel<<<(E + 255) / 256, 256, 0, stream>>>(dst, deg, rank, E);
    scan1_kernel<<<NB, SCAN_BLK, 0, stream>>>(deg, row_ptr, partials, N);
    scan2_kernel<<<1, 128, 0, stream>>>(partials, NB);
    scan3_kernel<<<NB, SCAN_BLK, 0, stream>>>(row_ptr, partials, N, NB);
    scatter_kernel<<<(E + 255) / 256, 256, 0, stream>>>(src, dst, edge_feats, row_ptr, rank,
                                                        erec, E);

    const int NH = N * HEADS;
    const int gb = (NH + 255) / 256;
    const int gb_agg = (N + 39) / 40;   // 40 nodes per 256-thread block

    // layer 1: 6 -> 8, packed 64B records (1 line/edge gathers)
    node_kernel<6, 8, 64><<<gb, 256, 0, stream>>>(node_feats, W1, al1, ar1, rec1, nullptr,
                                                  nullptr, er, N);
    agg_kernel<8, 64, 0><<<gb_agg, 256, 0, stream>>>(row_ptr, erec, rec1, nullptr,
                                                     nullptr, er, ce + 0, b1, xmean, nullptr, N);
    // layer 2: 8 -> 16
    node_kernel<8, 16, 0><<<gb, 256, 0, stream>>>(xmean, W2, al2, ar2, nullptr, ft, el, er, N);
    agg_kernel<16, 0, 0><<<gb_agg, 256, 0, stream>>>(row_ptr, erec, nullptr, ft,
                                                     el, er, ce + 3, b2, xmean, nullptr, N);
    // layer 3: 16 -> 32, epilogue writes fp16 h3
    node_kernel<16, 32, 0><<<gb, 256, 0, stream>>>(xmean, W3, al3, ar3, nullptr, ft, el, er, N);
    agg_kernel<32, 0, 1><<<gb_agg, 256, 0, stream>>>(row_ptr, erec, nullptr, ft,
                                                     el, er, ce + 6, b3, nullptr, h3, N);

    // MLP head + global max (fp16 h3)
    mlp_max_kernel<<<(N + 255) / 256, 256, 0, stream>>>(h3, l1w, l1b, l2w, l2b, l3w, l3b,
                                                        l4w, l4b, mkey, N);
    finalize_kernel<<<1, 1, 0, stream>>>(mkey, (float*)d_out);
}